// Round 5
// baseline (201.463 us; speedup 1.0000x reference)
//
#include <hip/hip_runtime.h>
#include <hip/hip_bf16.h>

#define B_NUM 4096
#define N_NUM 2048
#define E_NUM 1638
#define OUT_NUM 512
#define NTOT 2560   // N_NUM + OUT_NUM
#define KDIM 2048
#define NKT 32      // K tiles of 64

typedef unsigned short u16;
typedef __attribute__((ext_vector_type(8))) __bf16 bf16x8;
typedef __attribute__((ext_vector_type(4))) float f32x4;

__device__ __forceinline__ u16 f2bf(float f) {
  union { float f; unsigned u; } v; v.f = f;
  unsigned r = v.u + 0x7fffu + ((v.u >> 16) & 1u);
  return (u16)(r >> 16);
}

__device__ __forceinline__ void gload16(const u16* src, u16* dst) {
  __builtin_amdgcn_global_load_lds((__attribute__((address_space(1))) void*)src,
                                   (__attribute__((address_space(3))) void*)dst,
                                   16, 0, 0);
}

#define BAR() do { asm volatile("" ::: "memory"); \
                   __builtin_amdgcn_s_barrier();  \
                   asm volatile("" ::: "memory"); } while (0)

// ---------------- prep_u: u = relu(0.9*x + 0.1*(i + b)) ----------------
__global__ __launch_bounds__(256) void prep_u(const float* __restrict__ in_i,
                                              const float* __restrict__ in_x,
                                              const float* __restrict__ bias,
                                              float* __restrict__ u_f32,
                                              u16* __restrict__ u_bf16) {
  const int t = blockIdx.x * 256 + threadIdx.x;
  const int e = t * 4;
  const float4 iv = *(const float4*)(in_i + e);
  const float4 xv = *(const float4*)(in_x + e);
  const float4 bv = *(const float4*)(bias + (e & (N_NUM - 1)));
  float4 u;
  u.x = fmaxf(0.f, 0.9f * xv.x + 0.1f * (iv.x + bv.x));
  u.y = fmaxf(0.f, 0.9f * xv.y + 0.1f * (iv.y + bv.y));
  u.z = fmaxf(0.f, 0.9f * xv.z + 0.1f * (iv.z + bv.z));
  u.w = fmaxf(0.f, 0.9f * xv.w + 0.1f * (iv.w + bv.w));
  *(float4*)(u_f32 + e) = u;
  ushort4 ub;
  ub.x = f2bf(u.x); ub.y = f2bf(u.y); ub.z = f2bf(u.z); ub.w = f2bf(u.w);
  *(ushort4*)(u_bf16 + e) = ub;
}

// ---------------- prep_w: Wt[n][k] = signs[k]*|W[k][n]|, transposed, bf16 --
__global__ __launch_bounds__(256) void prep_w(const float* __restrict__ r,
                                              const float* __restrict__ f,
                                              u16* __restrict__ wt) {
  __shared__ u16 ldsT[64][72];
  const int k0 = blockIdx.y * 64;
  const int n0 = blockIdx.x * 64;
  const int tid = threadIdx.x;
  const int rloc = tid >> 4;
  const int c4 = (tid & 15) * 4;
#pragma unroll
  for (int rr = 0; rr < 4; ++rr) {
    const int kl = rr * 16 + rloc;
    const int k = k0 + kl;
    const float sign = (k < E_NUM) ? 1.f : -1.f;
    float4 v;
    if (n0 < N_NUM) v = *(const float4*)(r + k * N_NUM + n0 + c4);
    else            v = *(const float4*)(f + k * OUT_NUM + (n0 - N_NUM) + c4);
    float vals[4] = {v.x, v.y, v.z, v.w};
#pragma unroll
    for (int j = 0; j < 4; ++j) {
      float val = sign * fabsf(vals[j]);
      if (n0 < N_NUM && (n0 + c4 + j) == k) val = 0.f;
      ldsT[c4 + j][kl] = f2bf(val);
    }
  }
  __syncthreads();
  const int nl = tid >> 2;
  const int kc = (tid & 3) * 16;
  u16* dst = wt + (n0 + nl) * KDIM + k0 + kc;
  *(uint4*)(dst) = *(const uint4*)&ldsT[nl][kc];
  *(uint4*)(dst + 8) = *(const uint4*)&ldsT[nl][kc + 8];
}

// ---------------- gemm8q: 256x256, BK=64, 8 waves, 8-phase quadrant ------
// C = U[4096x2048] @ Wt^T.  m201-style: per 2 K-tiles, 8 phases of
// {ds_read subtile || stage 1 half-tile -> BAR -> setprio1 16 MFMA setprio0
//  -> [vmcnt(4) at ph3/ph7] -> BAR}.
// Waves 2Mx4N, wave tile 128x64. Per K-tile phases = C-quadrants:
//   Q(0,0): read A-lo(8) B n01(4); Q(0,1): read B n23(4), A reuse;
//   Q(1,0): read A-hi(8), B n01 reuse; Q(1,1): all reuse (0 reads).
// Stage map (iter T=2i): ph0:A(T+1)lo ph1:A(T+1)hi ph2:B(T+2)lo ph3:B(T+2)hi
//   ph4:A(T+2)lo ph5:A(T+2)hi ph6:B(T+3)lo ph7:B(T+3)hi.
// WAR: each stage is >=1 barrier after its target's last lgkm-drained read
//   (A(T) free after ph2, B(T) after ph1, A(T+1) after ph6, B(T+1) after ph5).
// RAW: F1=vmcnt(4)@ph3 covers {prev ph6,7, ph0,1} -> ph4's A(T+1)/B(T+1) ok;
//   F2=vmcnt(4)@ph7 covers through ph5 -> next ph0's A/B(T+2) ok.
// Buffers: buf0 = even K-tiles, buf1 = odd. Tail: clamp DATA kt, pin buffer
//   index explicitly -> clamped stages rewrite only dead-or-identical bytes.
__global__ __launch_bounds__(512, 2) void gemm8q(const u16* __restrict__ U,
                                                 const u16* __restrict__ Wt,
                                                 float* __restrict__ out) {
  __shared__ u16 lds[2][2][2][128 * 64];  // [dbuf][A/B][half][128x64], 128 KiB
  const int t = threadIdx.x;
  const int w = t >> 6, lane = t & 63;
  const int lr = lane & 15, lg = lane >> 4;
  const int wm = w >> 2, wn = w & 3;      // wave tile 128x64 at (wm*128, wn*64)
  const int hB = wn >> 1;                 // B half this wave reads
  const int row0 = blockIdx.y * 256;
  const int col0 = blockIdx.x * 256;

  // staging: wave w, shot s in {0,1} covers half-tile rows (w+8s)*8+(lane>>3),
  // phys colbyte (lane&7)*16; pre-swizzled global col = 16*((lane&7)^(lane>>3))
  const int sg = w * 8 + (lane >> 3);
  const int koff = 8 * ((lane & 7) ^ (lane >> 3));
  const u16* aBase = U + (row0 + sg) * KDIM + koff;
  const u16* bBase = Wt + (col0 + sg) * KDIM + koff;

  // fragment reads: row-in-half R, phys col u16 = ((ks*64+lg*16)^((R&7)<<4))>>1
  const int xs = (lr & 7) << 4;
  const int ca0 = ((lg * 16) ^ xs) >> 1;
  const int ca1 = ((64 + lg * 16) ^ xs) >> 1;

  f32x4 acc[8][4] = {};
  bf16x8 af[4][2], b0[2][2], b1[2][2];

#define STA(c, h, kt) { const u16* g_ = aBase + (h) * 128 * KDIM + (kt) * 64;  \
  gload16(g_,             &lds[c][0][h][w * 512]);                             \
  gload16(g_ + 64 * KDIM, &lds[c][0][h][(w + 8) * 512]); }
#define STB(c, h, kt) { const u16* g_ = bBase + (h) * 128 * KDIM + (kt) * 64;  \
  gload16(g_,             &lds[c][1][h][w * 512]);                             \
  gload16(g_ + 64 * KDIM, &lds[c][1][h][(w + 8) * 512]); }
#define RD_A(c, mq) { _Pragma("unroll") for (int mi = 0; mi < 4; ++mi) {       \
    const int R_ = ((mq) * 64 + mi * 16 + lr) * 64;                            \
    af[mi][0] = *(const bf16x8*)&lds[c][0][wm][R_ + ca0];                      \
    af[mi][1] = *(const bf16x8*)&lds[c][0][wm][R_ + ca1]; } }
#define RD_B(c, dst, nq) { _Pragma("unroll") for (int ni = 0; ni < 2; ++ni) {  \
    const int R_ = ((wn & 1) * 64 + ((nq) * 2 + ni) * 16 + lr) * 64;           \
    dst[ni][0] = *(const bf16x8*)&lds[c][1][hB][R_ + ca0];                     \
    dst[ni][1] = *(const bf16x8*)&lds[c][1][hB][R_ + ca1]; } }
#define QMFMA(MQ, NQ, bX) { __builtin_amdgcn_s_setprio(1);                     \
  _Pragma("unroll") for (int mi = 0; mi < 4; ++mi)                             \
    _Pragma("unroll") for (int ni = 0; ni < 2; ++ni) {                         \
      acc[(MQ)*4+mi][(NQ)*2+ni] = __builtin_amdgcn_mfma_f32_16x16x32_bf16(     \
          af[mi][0], bX[ni][0], acc[(MQ)*4+mi][(NQ)*2+ni], 0, 0, 0);           \
      acc[(MQ)*4+mi][(NQ)*2+ni] = __builtin_amdgcn_mfma_f32_16x16x32_bf16(     \
          af[mi][1], bX[ni][1], acc[(MQ)*4+mi][(NQ)*2+ni], 0, 0, 0); }         \
  __builtin_amdgcn_s_setprio(0); }
#define FENCE4() do { asm volatile("s_waitcnt vmcnt(4)" ::: "memory");         \
                      __builtin_amdgcn_sched_barrier(0); } while (0)

  // prologue: buf0 complete (8 loads) + B(1) (4 loads); retire buf0
  STA(0, 0, 0); STA(0, 1, 0); STB(0, 0, 0); STB(0, 1, 0);
  STB(1, 0, 1); STB(1, 1, 1);
  FENCE4();
  BAR();

  for (int it = 0; it < NKT / 2; ++it) {
    const int T = 2 * it;
    const int Tc2 = (T + 2 < NKT) ? T + 2 : NKT - 1;
    const int Tc3 = (T + 3 < NKT) ? T + 3 : NKT - 1;
    // ============== K-tile T (buf0) ==============
    RD_A(0, 0); RD_B(0, b0, 0);          // ph0: Q(0,0)
    STA(1, 0, T + 1);
    BAR(); QMFMA(0, 0, b0); BAR();
    RD_B(0, b1, 1);                      // ph1: Q(0,1)
    STA(1, 1, T + 1);
    BAR(); QMFMA(0, 1, b1); BAR();
    RD_A(0, 1);                          // ph2: Q(1,0)
    STB(0, 0, Tc2);
    BAR(); QMFMA(1, 0, b0); BAR();
    STB(0, 1, Tc2);                      // ph3: Q(1,1)
    BAR(); QMFMA(1, 1, b1);
    FENCE4(); BAR();
    // ============== K-tile T+1 (buf1) ==============
    RD_A(1, 0); RD_B(1, b0, 0);          // ph4: Q(0,0)
    STA(0, 0, Tc2);
    BAR(); QMFMA(0, 0, b0); BAR();
    RD_B(1, b1, 1);                      // ph5: Q(0,1)
    STA(0, 1, Tc2);
    BAR(); QMFMA(0, 1, b1); BAR();
    RD_A(1, 1);                          // ph6: Q(1,0)
    STB(1, 0, Tc3);
    BAR(); QMFMA(1, 0, b0); BAR();
    STB(1, 1, Tc3);                      // ph7: Q(1,1)
    BAR(); QMFMA(1, 1, b1);
    FENCE4(); BAR();
  }
  asm volatile("s_waitcnt vmcnt(0)" ::: "memory");  // drain DMA before exit

  // epilogue: C/D map col=lane&15, row=(lane>>4)*4+q
  const int orow = row0 + wm * 128 + lg * 4;
  const int ocol = col0 + wn * 64 + lr;
  if (col0 < N_NUM) {           // whole tile -> r_out
    float* ro = out + B_NUM * OUT_NUM;
#pragma unroll
    for (int mi = 0; mi < 8; ++mi)
#pragma unroll
      for (int ni = 0; ni < 4; ++ni)
#pragma unroll
        for (int q = 0; q < 4; ++q)
          ro[(orow + mi * 16 + q) * N_NUM + ocol + ni * 16] = acc[mi][ni][q];
  } else {                      // whole tile -> f_out
#pragma unroll
    for (int mi = 0; mi < 8; ++mi)
#pragma unroll
      for (int ni = 0; ni < 4; ++ni)
#pragma unroll
        for (int q = 0; q < 4; ++q)
          out[(orow + mi * 16 + q) * OUT_NUM + (ocol - N_NUM) + ni * 16] = acc[mi][ni][q];
  }
#undef STA
#undef STB
#undef RD_A
#undef RD_B
#undef QMFMA
#undef FENCE4
}

extern "C" void kernel_launch(void* const* d_in, const int* in_sizes, int n_in,
                              void* d_out, int out_size, void* d_ws, size_t ws_size,
                              hipStream_t stream) {
  const float* i_ = (const float*)d_in[0];
  const float* x  = (const float*)d_in[1];
  const float* r  = (const float*)d_in[2];
  const float* f  = (const float*)d_in[3];
  const float* b  = (const float*)d_in[4];
  float* out = (float*)d_out;

  u16* U  = (u16*)d_ws;                                      // 16 MB
  u16* Wt = (u16*)((char*)d_ws + (size_t)B_NUM * KDIM * 2);  // 10 MB

  float* u_region = out + (size_t)B_NUM * OUT_NUM + (size_t)B_NUM * N_NUM;

  prep_u<<<(B_NUM * N_NUM / 4) / 256, 256, 0, stream>>>(i_, x, b, u_region, U);
  prep_w<<<dim3(NTOT / 64, N_NUM / 64), 256, 0, stream>>>(r, f, Wt);
  gemm8q<<<dim3(NTOT / 256, B_NUM / 256), 512, 0, stream>>>(U, Wt, out);
}